// Round 1
// baseline (902.074 us; speedup 1.0000x reference)
//
#include <hip/hip_runtime.h>
#include <hip/hip_fp16.h>

typedef _Float16 f16;
typedef _Float16 f16x8 __attribute__((ext_vector_type(8)));
typedef _Float16 f16x4 __attribute__((ext_vector_type(4)));
typedef float f32x4 __attribute__((ext_vector_type(4)));

#define SEQ 2048
#define BATCH 8
#define NCHUNK 16  // row chunks for colstats partials

// ---------------------------------------------------------------- helpers
__device__ __forceinline__ void gl2lds16(const f16* g, f16* l) {
  // 16B-wide async global->LDS. LDS dest is wave-uniform base; HW adds lane*16.
  __builtin_amdgcn_global_load_lds((const __attribute__((address_space(1))) void*)g,
                                   (__attribute__((address_space(3))) void*)l,
                                   16, 0, 0);
}

// ---------------------------------------------------------------- cast fp32 -> fp16
__global__ __launch_bounds__(256) void cast_kernel(const float* __restrict__ in,
                                                   f16* __restrict__ out, int n4) {
  int i = blockIdx.x * 256 + threadIdx.x;
  if (i < n4) {
    float4 v = ((const float4*)in)[i];
    f16x4 h;
    h[0] = (f16)v.x; h[1] = (f16)v.y; h[2] = (f16)v.z; h[3] = (f16)v.w;
    ((f16x4*)out)[i] = h;
  }
}

// ---------------------------------------------------------------- GEMM  C[m][n] = sum_k A[m][k] * Bt[n][k]
// m97-ladder structure: 128x128 tile, BK=64, 4 waves (2x2 of 64x64), each wave
// a 4x4 grid of mfma_f32_16x16x32_f16. global_load_lds(16B) staging with
// XOR-swizzled LDS (linear dest + pre-swizzled global source + swizzled ds_read).
__global__ __launch_bounds__(256) void gemm_nt(const f16* __restrict__ A,
                                               const f16* __restrict__ Bt,
                                               float* __restrict__ C,
                                               int K, int N,
                                               long long sA, long long sB, long long sC) {
  const f16* Ab = A + blockIdx.z * sA;
  const f16* Bb = Bt + blockIdx.z * sB;
  float* Cb = C + blockIdx.z * sC;
  const int m0 = blockIdx.y * 128, n0 = blockIdx.x * 128;

  __shared__ f16 As[128][64];   // 16 KB, row stride 128B
  __shared__ f16 Bs[128][64];   // 16 KB

  const int tid = threadIdx.x;
  const int wave = tid >> 6, lane = tid & 63;
  const int wm = (wave >> 1) << 6;      // wave row offset (0/64)
  const int wn = (wave & 1) << 6;       // wave col offset (0/64)
  const int l15 = lane & 15, h = lane >> 4;  // mfma 16x16x32: row/col = l15, k-chunk = h

  // staging: each wave-issue covers 8 rows x 64 cols (1KB linear LDS).
  // lane l -> LDS row rb + l/8, bytes (l&7)*16. Swizzle: stored[r][b] = logical[r][b ^ ((r&7)<<4)]
  // -> pre-swizzled global source column:
  const int srow = lane >> 3;                  // 0..7 == row&7 within chunk
  const int scol = ((lane & 7) ^ srow) * 8;    // swizzled source col (elements)
  const f16* aSrc = Ab + (size_t)(m0 + wave * 8 + srow) * K + scol;
  const f16* bSrc = Bb + (size_t)(n0 + wave * 8 + srow) * K + scol;

  // read-side swizzled byte offset within a 128B row (kk=0); kk=1 toggles bit 6.
  const int roff = (h * 16) ^ ((l15 & 7) << 4);

  f32x4 acc[4][4];
#pragma unroll
  for (int i = 0; i < 4; i++)
#pragma unroll
    for (int j = 0; j < 4; j++)
#pragma unroll
      for (int r = 0; r < 4; r++) acc[i][j][r] = 0.f;

  for (int k0 = 0; k0 < K; k0 += 64) {
#pragma unroll
    for (int j = 0; j < 4; j++) {
      const int rb = (j * 4 + wave) * 8;   // wave-uniform LDS row base
      gl2lds16(aSrc + (size_t)(j * 32) * K + k0, &As[rb][0]);
      gl2lds16(bSrc + (size_t)(j * 32) * K + k0, &Bs[rb][0]);
    }
    __syncthreads();

#pragma unroll
    for (int kk = 0; kk < 2; kk++) {
      const int xo = roff ^ (kk << 6);
      f16x8 a[4], b[4];
#pragma unroll
      for (int i = 0; i < 4; i++) {
        a[i] = *(const f16x8*)((const char*)(&As[0][0]) + (wm + i * 16 + l15) * 128 + xo);
        b[i] = *(const f16x8*)((const char*)(&Bs[0][0]) + (wn + i * 16 + l15) * 128 + xo);
      }
#pragma unroll
      for (int i = 0; i < 4; i++)
#pragma unroll
        for (int j = 0; j < 4; j++)
          acc[i][j] = __builtin_amdgcn_mfma_f32_16x16x32_f16(a[i], b[j], acc[i][j], 0, 0, 0);
    }
    __syncthreads();
  }

  // epilogue: 16x16 C/D layout col=lane&15, row=(lane>>4)*4 + reg  [m89/m91]
#pragma unroll
  for (int i = 0; i < 4; i++) {
    const int rowb = m0 + wm + i * 16 + h * 4;
#pragma unroll
    for (int j = 0; j < 4; j++) {
      const int col = n0 + wn + j * 16 + l15;
#pragma unroll
      for (int r = 0; r < 4; r++)
        Cb[(size_t)(rowb + r) * N + col] = acc[i][j][r];
    }
  }
}

// ---------------------------------------------------------------- per-column online (max, sumexp) partials
// G[k][q] per batch; stats over k (rows) for each column q. Grid: (SEQ/256, NCHUNK, BATCH).
__global__ __launch_bounds__(256) void colstats_part(const float* __restrict__ G,
                                                     float* __restrict__ pm,
                                                     float* __restrict__ ps) {
  const int b = blockIdx.z, chunk = blockIdx.y;
  const int q = blockIdx.x * 256 + threadIdx.x;
  const int rows = SEQ / NCHUNK;  // 128
  const float* p = G + (size_t)b * SEQ * SEQ + (size_t)chunk * rows * SEQ + q;
  float m = -3.0e38f, s = 0.f;
#pragma unroll 4
  for (int k = 0; k < rows; k++) {
    float x = p[(size_t)k * SEQ];
    if (x > m) { s = s * __expf(m - x) + 1.f; m = x; }
    else       { s += __expf(x - m); }
  }
  const size_t o = ((size_t)chunk * BATCH + b) * SEQ + q;
  pm[o] = m;
  ps[o] = s;
}

// ---------------------------------------------------------------- combine partials -> m, 1/Z
__global__ __launch_bounds__(256) void colstats_combine(const float* __restrict__ pm,
                                                        const float* __restrict__ ps,
                                                        float* __restrict__ mrow,
                                                        float* __restrict__ rzrow) {
  const int b = blockIdx.y;
  const int q = blockIdx.x * 256 + threadIdx.x;
  float m = -3.0e38f, s = 0.f;
#pragma unroll
  for (int c = 0; c < NCHUNK; c++) {
    const size_t o = ((size_t)c * BATCH + b) * SEQ + q;
    float mc = pm[o], sc = ps[o];
    if (mc > m) { s = s * __expf(m - mc) + sc; m = mc; }
    else        { s += sc * __expf(mc - m); }
  }
  mrow[(size_t)b * SEQ + q] = m;
  rzrow[(size_t)b * SEQ + q] = 1.f / s;
}

// ---------------------------------------------------------------- PT[k][q] = exp(G[k][q]-m[q])/Z[q], fp16
__global__ __launch_bounds__(256) void scale_kernel(const float* __restrict__ G,
                                                    const float* __restrict__ mrow,
                                                    const float* __restrict__ rzrow,
                                                    f16* __restrict__ PT) {
  const int i = blockIdx.x * 256 + threadIdx.x;   // float4 index, < 2^23
  const int b = i >> 20;                          // SEQ*SEQ/4 = 2^20 per batch
  const int cg = i & (SEQ / 4 - 1);               // column group
  float4 g = ((const float4*)G)[i];
  float4 m4 = ((const float4*)(mrow + (size_t)b * SEQ))[cg];
  float4 z4 = ((const float4*)(rzrow + (size_t)b * SEQ))[cg];
  f16x4 o;
  o[0] = (f16)(__expf(g.x - m4.x) * z4.x);
  o[1] = (f16)(__expf(g.y - m4.y) * z4.y);
  o[2] = (f16)(__expf(g.z - m4.z) * z4.z);
  o[3] = (f16)(__expf(g.w - m4.w) * z4.w);
  ((f16x4*)PT)[i] = o;
}

// ---------------------------------------------------------------- launch
extern "C" void kernel_launch(void* const* d_in, const int* in_sizes, int n_in,
                              void* d_out, int out_size, void* d_ws, size_t ws_size,
                              hipStream_t stream) {
  const float* Q = (const float*)d_in[0];
  const float* Kf = (const float*)d_in[1];
  const float* V = (const float*)d_in[2];
  // d_in[3] attn_mask: all zeros, unused by the reference.
  float* out = (float*)d_out;

  const size_t nElem = (size_t)BATCH * SEQ * SEQ;  // 33,554,432
  f16* Qh = (f16*)d_ws;
  f16* Kh = Qh + nElem;
  f16* Vh = Kh + nElem;
  f16* PT = Vh + nElem;
  float* G = (float*)(PT + nElem);                 // qk^T: G[b][k][q]
  float* mrow = G + nElem;
  float* rzrow = mrow + (size_t)BATCH * SEQ;
  // partials overlay Qh's region (Qh is dead after GEMM1; partials written after GEMM1)
  float* pm = (float*)Qh;
  float* ps = pm + (size_t)NCHUNK * BATCH * SEQ;
  // total ws use unchanged: ~403 MB

  const int n4 = (int)(nElem / 4);
  dim3 cgrid(n4 / 256);
  cast_kernel<<<cgrid, 256, 0, stream>>>(Q, Qh, n4);
  cast_kernel<<<cgrid, 256, 0, stream>>>(Kf, Kh, n4);
  cast_kernel<<<cgrid, 256, 0, stream>>>(V, Vh, n4);

  const long long sb = (long long)SEQ * SEQ;
  dim3 ggrid(SEQ / 128, SEQ / 128, BATCH);  // 16x16x8
  // G[k][q] = sum_d K[k][d] * Q[q][d]  ( = qk[q][k] transposed )
  gemm_nt<<<ggrid, 256, 0, stream>>>(Kh, Qh, G, SEQ, SEQ, sb, sb, sb);

  colstats_part<<<dim3(SEQ / 256, NCHUNK, BATCH), 256, 0, stream>>>(G, pm, ps);
  colstats_combine<<<dim3(SEQ / 256, BATCH), 256, 0, stream>>>(pm, ps, mrow, rzrow);

  scale_kernel<<<dim3(n4 / 256), 256, 0, stream>>>(G, mrow, rzrow, PT);

  // out[s][n] = sum_d V[s][d] * PT[n][d]
  gemm_nt<<<ggrid, 256, 0, stream>>>(Vh, PT, out, SEQ, SEQ, sb, sb, sb);
}